// Round 1
// baseline (901.870 us; speedup 1.0000x reference)
//
#include <hip/hip_runtime.h>

#define EPS 1e-6f
#define INV_TEMP 0.31622776601683794f   // 1/sqrt(10)

#define THREADS 128
#define XSTRIDE 91                       // 91 mod 32 = 27 (odd) -> conflict-free

// d_ws layout (floats)
#define W1T_OFF   0        // 30x30 transposed:  [i*30+o]
#define W1PT_OFF  900      // 90x90 transposed:  [i*90+o]
#define WC1T_OFF  9000     // 90x45 transposed:  [i*45+o]  (Wc1 is [45,90])
// total 13050 floats = 52200 bytes

__global__ void prep_kernel(const float* __restrict__ W1,
                            const float* __restrict__ W1p,
                            const float* __restrict__ Wc1,
                            float* __restrict__ ws)
{
    int t = blockIdx.x * blockDim.x + threadIdx.x;
    int stride = gridDim.x * blockDim.x;
    for (int idx = t; idx < 900; idx += stride) {
        int i = idx / 30, o = idx % 30;
        ws[W1T_OFF + idx] = W1[o*30 + i];
    }
    for (int idx = t; idx < 8100; idx += stride) {
        int i = idx / 90, o = idx % 90;
        ws[W1PT_OFF + idx] = W1p[o*90 + i];
    }
    for (int idx = t; idx < 4050; idx += stride) {
        int i = idx / 45, o = idx % 45;
        ws[WC1T_OFF + idx] = Wc1[o*90 + i];
    }
}

// One branch of MHA: qb/kb/vb are 30-float register arrays (3 seq x 10 dim).
// Output (after residual + LN) written to LDS at xo[0..29].
__device__ __forceinline__ void mha_core(const float* qb, const float* kb, const float* vb,
    const float* __restrict__ Wq, const float* __restrict__ Wk, const float* __restrict__ Wv,
    const float* __restrict__ g, const float* __restrict__ b,
    float* xo)
{
    float qh[30], kh[30], vh[30];
#pragma unroll
    for (int s = 0; s < 3; ++s) {
#pragma unroll
        for (int o = 0; o < 10; ++o) {
            float aq = 0.f, ak = 0.f, av = 0.f;
#pragma unroll
            for (int i = 0; i < 10; ++i) {
                aq = fmaf(qb[s*10+i], Wq[o*10+i], aq);
                ak = fmaf(kb[s*10+i], Wk[o*10+i], ak);
                av = fmaf(vb[s*10+i], Wv[o*10+i], av);
            }
            qh[s*10+o] = aq * INV_TEMP;
            kh[s*10+o] = ak;
            vh[s*10+o] = av;
        }
    }
    float attn[9];
#pragma unroll
    for (int s = 0; s < 3; ++s) {
#pragma unroll
        for (int t = 0; t < 3; ++t) {
            float a = 0.f;
#pragma unroll
            for (int o = 0; o < 10; ++o) a = fmaf(qh[s*10+o], kh[t*10+o], a);
            attn[s*3+t] = a;
        }
    }
#pragma unroll
    for (int s = 0; s < 3; ++s) {
        float o10[10];
        float sum = 0.f;
#pragma unroll
        for (int d = 0; d < 10; ++d) {
            float x = qb[s*10+d];                 // residual
            x = fmaf(attn[s*3+0], vh[ 0+d], x);
            x = fmaf(attn[s*3+1], vh[10+d], x);
            x = fmaf(attn[s*3+2], vh[20+d], x);
            o10[d] = x;
            sum += x;
        }
        float m = sum * 0.1f;
        float var = 0.f;
#pragma unroll
        for (int d = 0; d < 10; ++d) { float dd = o10[d] - m; var = fmaf(dd, dd, var); }
        var *= 0.1f;
        float r = rsqrtf(var + EPS);
#pragma unroll
        for (int d = 0; d < 10; ++d)
            xo[s*10+d] = fmaf((o10[d] - m) * r, g[d], b[d]);
    }
}

// PFF on a D-vector living in LDS at xl[0..D-1] (per-thread region).
// Layer1: roll i (ds_read x), unroll o into register accumulators h[D];
//         weights W1T transposed -> contiguous s_load rows.
// Layer2: roll o, unroll i over register h; original W2 rows contiguous;
//         in-place overwrite of xl[o] (residual consumed at that moment),
//         running sum/sumsq for LN; then rolled normalize pass.
template<int D>
__device__ __forceinline__ void pff_lds(float* xl,
    const float* __restrict__ W1T, const float* __restrict__ b1,
    const float* __restrict__ W2,  const float* __restrict__ b2,
    const float* __restrict__ g,   const float* __restrict__ bb)
{
    float h[D];
#pragma unroll
    for (int o = 0; o < D; ++o) h[o] = b1[o];
#pragma unroll 1
    for (int i = 0; i < D; ++i) {
        float xi = xl[i];
        const float* wr = W1T + i*D;
#pragma unroll
        for (int o = 0; o < D; ++o) h[o] = fmaf(xi, wr[o], h[o]);
    }
#pragma unroll
    for (int o = 0; o < D; ++o) h[o] = fmaxf(h[o], 0.f);

    float sum = 0.f, sumsq = 0.f;
#pragma unroll 1
    for (int o = 0; o < D; ++o) {
        const float* wr = W2 + o*D;
        float acc = b2[o] + xl[o];            // bias + residual
#pragma unroll
        for (int i = 0; i < D; ++i) acc = fmaf(h[i], wr[i], acc);
        xl[o] = acc;
        sum += acc;
        sumsq = fmaf(acc, acc, sumsq);
    }
    const float invD = 1.f / (float)D;
    float m = sum * invD;
    float var = sumsq * invD - m * m;
    float r = rsqrtf(var + EPS);
#pragma unroll 1
    for (int o = 0; o < D; ++o)
        xl[o] = fmaf((xl[o] - m) * r, g[o], bb[o]);
}

__global__ __launch_bounds__(THREADS) void moct_kernel(
    const float* __restrict__ q, const float* __restrict__ k, const float* __restrict__ v,
    const float* __restrict__ Wq, const float* __restrict__ Wk, const float* __restrict__ Wv,
    const float* __restrict__ g_mha, const float* __restrict__ b_mha,
    const float* __restrict__ b1, const float* __restrict__ W2, const float* __restrict__ b2,
    const float* __restrict__ g_pff, const float* __restrict__ b_pff,
    const float* __restrict__ b1p, const float* __restrict__ W2p, const float* __restrict__ b2p,
    const float* __restrict__ g_pff1, const float* __restrict__ b_pff1,
    const float* __restrict__ bc1, const float* __restrict__ Wc2, const float* __restrict__ bc2,
    const float* __restrict__ ws,
    float* __restrict__ out, int nrows)
{
    __shared__ float xbuf[THREADS * XSTRIDE];
    const int row = blockIdx.x * THREADS + threadIdx.x;
    if (row >= nrows) return;                 // no __syncthreads anywhere: safe
    float* xl = xbuf + threadIdx.x * XSTRIDE;

    const float* W1T  = ws + W1T_OFF;
    const float* W1pT = ws + W1PT_OFF;
    const float* Wc1T = ws + WC1T_OFF;

    const size_t rbase = (size_t)row * 90;

    // ---- stage 1: MHA(q,k,v) -> x[90] in LDS ----
#pragma unroll 1
    for (int br = 0; br < 3; ++br) {
        float qb[30], kb[30], vb[30];
        const float2* qp = (const float2*)(q + rbase + br*30);
        const float2* kp = (const float2*)(k + rbase + br*30);
        const float2* vp = (const float2*)(v + rbase + br*30);
#pragma unroll
        for (int j = 0; j < 15; ++j) {
            float2 t0 = qp[j]; qb[2*j] = t0.x; qb[2*j+1] = t0.y;
            float2 t1 = kp[j]; kb[2*j] = t1.x; kb[2*j+1] = t1.y;
            float2 t2 = vp[j]; vb[2*j] = t2.x; vb[2*j+1] = t2.y;
        }
        mha_core(qb, kb, vb, Wq, Wk, Wv, g_mha, b_mha, xl + br*30);
    }

    // ---- stage 2: PFF30 per branch ----
#pragma unroll 1
    for (int br = 0; br < 3; ++br)
        pff_lds<30>(xl + br*30, W1T, b1, W2, b2, g_pff, b_pff);

    // ---- stage 3: MHA(x,x,x) per branch ----
#pragma unroll 1
    for (int br = 0; br < 3; ++br) {
        float xb[30];
#pragma unroll
        for (int j = 0; j < 30; ++j) xb[j] = xl[br*30 + j];
        mha_core(xb, xb, xb, Wq, Wk, Wv, g_mha, b_mha, xl + br*30);
    }

    // ---- stage 4: PFF30 per branch ----
#pragma unroll 1
    for (int br = 0; br < 3; ++br)
        pff_lds<30>(xl + br*30, W1T, b1, W2, b2, g_pff, b_pff);

    // ---- stage 5: PFF90 on full 90-vector ----
    pff_lds<90>(xl, W1pT, b1p, W2p, b2p, g_pff1, b_pff1);

    // ---- classifier ----
    float c1[45];
#pragma unroll
    for (int o = 0; o < 45; ++o) c1[o] = bc1[o];
#pragma unroll 1
    for (int i = 0; i < 90; ++i) {
        float xi = xl[i];
        const float* wr = Wc1T + i*45;
#pragma unroll
        for (int o = 0; o < 45; ++o) c1[o] = fmaf(xi, wr[o], c1[o]);
    }
#pragma unroll
    for (int o = 0; o < 45; ++o) c1[o] = fmaxf(c1[o], 0.f);

    float lg[3];
#pragma unroll
    for (int c = 0; c < 3; ++c) {
        float acc = bc2[c];
        const float* wr = Wc2 + c*45;
#pragma unroll
        for (int i = 0; i < 45; ++i) acc = fmaf(c1[i], wr[i], acc);
        lg[c] = acc;
    }
    float mx = fmaxf(lg[0], fmaxf(lg[1], lg[2]));
    float e0 = __expf(lg[0]-mx), e1 = __expf(lg[1]-mx), e2 = __expf(lg[2]-mx);
    float inv = 1.f / (e0 + e1 + e2);
    out[row*3+0] = e0*inv;
    out[row*3+1] = e1*inv;
    out[row*3+2] = e2*inv;
}

extern "C" void kernel_launch(void* const* d_in, const int* in_sizes, int n_in,
                              void* d_out, int out_size, void* d_ws, size_t ws_size,
                              hipStream_t stream)
{
    const float* q     = (const float*)d_in[0];
    const float* k     = (const float*)d_in[1];
    const float* v     = (const float*)d_in[2];
    const float* Wq    = (const float*)d_in[3];
    const float* Wk    = (const float*)d_in[4];
    const float* Wv    = (const float*)d_in[5];
    const float* g_mha = (const float*)d_in[6];
    const float* b_mha = (const float*)d_in[7];
    const float* W1    = (const float*)d_in[8];
    const float* b1    = (const float*)d_in[9];
    const float* W2    = (const float*)d_in[10];
    const float* b2    = (const float*)d_in[11];
    const float* g_pff = (const float*)d_in[12];
    const float* b_pff = (const float*)d_in[13];
    const float* W1p   = (const float*)d_in[14];
    const float* b1p   = (const float*)d_in[15];
    const float* W2p   = (const float*)d_in[16];
    const float* b2p   = (const float*)d_in[17];
    const float* g_pff1= (const float*)d_in[18];
    const float* b_pff1= (const float*)d_in[19];
    const float* Wc1   = (const float*)d_in[20];
    const float* bc1   = (const float*)d_in[21];
    const float* Wc2   = (const float*)d_in[22];
    const float* bc2   = (const float*)d_in[23];

    float* ws = (float*)d_ws;
    const int nrows = in_sizes[0] / 90;

    hipLaunchKernelGGL(prep_kernel, dim3(52), dim3(256), 0, stream, W1, W1p, Wc1, ws);

    const int grid = (nrows + THREADS - 1) / THREADS;
    hipLaunchKernelGGL(moct_kernel, dim3(grid), dim3(THREADS), 0, stream,
        q, k, v, Wq, Wk, Wv, g_mha, b_mha,
        b1, W2, b2, g_pff, b_pff,
        b1p, W2p, b2p, g_pff1, b_pff1,
        bc1, Wc2, bc2, ws, (float*)d_out, nrows);
}

// Round 2
// 733.740 us; speedup vs baseline: 1.2291x; 1.2291x over previous
//
#include <hip/hip_runtime.h>

#define EPS 1e-6f
#define INV_TEMP 0.31622776601683794f   // 1/sqrt(10)

#define THREADS 128
#define XSTRIDE 91                       // 91 mod 32 = 27 -> 2 lanes/bank (free)

// d_ws layout (float offsets), all rows padded to 16B multiples
#define W1T_OFF   0        // 30 x 32  [i*32+o]   W1 transposed
#define W2C_OFF   960      // 30 x 32  [o*32+i]   W2 padded copy
#define W1PT_OFF  1920     // 90 x 92  [i*92+o]   W1p transposed
#define W2PC_OFF  10200    // 90 x 92  [o*92+i]   W2p padded copy
#define WC1T_OFF  18480    // 90 x 48  [i*48+o]   Wc1 transposed ([45,90] -> [90,45])
#define WQC_OFF   22800    // 10 x 12  [o*12+i]
#define WKC_OFF   22920
#define WVC_OFF   23040
// total 23160 floats = 92640 bytes

__global__ void prep_kernel(const float* __restrict__ W1, const float* __restrict__ W2,
                            const float* __restrict__ W1p, const float* __restrict__ W2p,
                            const float* __restrict__ Wc1,
                            const float* __restrict__ Wq, const float* __restrict__ Wk,
                            const float* __restrict__ Wv,
                            float* __restrict__ ws)
{
    int t = blockIdx.x * blockDim.x + threadIdx.x;
    int stride = gridDim.x * blockDim.x;
    for (int idx = t; idx < 900; idx += stride) {
        int r = idx / 30, c = idx % 30;
        ws[W1T_OFF + r*32 + c] = W1[c*30 + r];   // transpose
        ws[W2C_OFF + r*32 + c] = W2[r*30 + c];   // padded copy
    }
    for (int idx = t; idx < 8100; idx += stride) {
        int r = idx / 90, c = idx % 90;
        ws[W1PT_OFF + r*92 + c] = W1p[c*90 + r]; // transpose
        ws[W2PC_OFF + r*92 + c] = W2p[r*90 + c]; // padded copy
    }
    for (int idx = t; idx < 4050; idx += stride) {
        int i = idx / 45, o = idx % 45;
        ws[WC1T_OFF + i*48 + o] = Wc1[o*90 + i]; // transpose [45,90]->[90,45]
    }
    for (int idx = t; idx < 100; idx += stride) {
        int o = idx / 10, i = idx % 10;
        ws[WQC_OFF + o*12 + i] = Wq[o*10 + i];
        ws[WKC_OFF + o*12 + i] = Wk[o*10 + i];
        ws[WVC_OFF + o*12 + i] = Wv[o*10 + i];
    }
}

// One branch of MHA on register arrays (3 seq x 10 dim). Weights padded stride 12.
// Writes LN'd output to xo[0..29] (LDS).
__device__ __forceinline__ void mha_core(const float* qb, const float* kb, const float* vb,
    const float* Wq, const float* Wk, const float* Wv,
    const float* g, const float* b, float* xo)
{
    float qh[30], kh[30], vh[30];
#pragma unroll
    for (int s = 0; s < 3; ++s) {
#pragma unroll
        for (int o = 0; o < 10; ++o) {
            float aq = 0.f, ak = 0.f, av = 0.f;
#pragma unroll
            for (int i = 0; i < 10; ++i) {
                aq = fmaf(qb[s*10+i], Wq[o*12+i], aq);
                ak = fmaf(kb[s*10+i], Wk[o*12+i], ak);
                av = fmaf(vb[s*10+i], Wv[o*12+i], av);
            }
            qh[s*10+o] = aq * INV_TEMP;
            kh[s*10+o] = ak;
            vh[s*10+o] = av;
        }
    }
    float attn[9];
#pragma unroll
    for (int s = 0; s < 3; ++s) {
#pragma unroll
        for (int t = 0; t < 3; ++t) {
            float a0 = 0.f, a1 = 0.f;
#pragma unroll
            for (int o = 0; o < 5; ++o) {
                a0 = fmaf(qh[s*10+o],   kh[t*10+o],   a0);
                a1 = fmaf(qh[s*10+5+o], kh[t*10+5+o], a1);
            }
            attn[s*3+t] = a0 + a1;
        }
    }
#pragma unroll
    for (int s = 0; s < 3; ++s) {
        float o10[10];
        float sum = 0.f;
#pragma unroll
        for (int d = 0; d < 10; ++d) {
            float x = qb[s*10+d];                 // residual
            x = fmaf(attn[s*3+0], vh[ 0+d], x);
            x = fmaf(attn[s*3+1], vh[10+d], x);
            x = fmaf(attn[s*3+2], vh[20+d], x);
            o10[d] = x;
            sum += x;
        }
        float m = sum * 0.1f;
        float var = 0.f;
#pragma unroll
        for (int d = 0; d < 10; ++d) { float dd = o10[d] - m; var = fmaf(dd, dd, var); }
        var *= 0.1f;
        float r = rsqrtf(var + EPS);
#pragma unroll
        for (int d = 0; d < 10; ++d)
            xo[s*10+d] = fmaf((o10[d] - m) * r, g[d], b[d]);
    }
}

// PFF30 on all 3 branches jointly. Input xl is already LN'd (materialized).
// Output: RAW (pre-LN) y written to xl; per-branch (mean, rstd) returned.
__device__ __forceinline__ void pff30x3(float* xl,
    const float* W1T, const float* W2C, const float* b1v, const float* b2v,
    float* m, float* r)
{
    float h[90];
#pragma unroll
    for (int o = 0; o < 30; ++o) { float bb = b1v[o]; h[o] = bb; h[30+o] = bb; h[60+o] = bb; }
#pragma unroll 2
    for (int i = 0; i < 30; ++i) {
        float x0 = xl[i], x1 = xl[30+i], x2 = xl[60+i];
        const float* wr = W1T + i*32;
#pragma unroll
        for (int o = 0; o < 30; ++o) {
            float w = wr[o];
            h[o]    = fmaf(x0, w, h[o]);
            h[30+o] = fmaf(x1, w, h[30+o]);
            h[60+o] = fmaf(x2, w, h[60+o]);
        }
    }
#pragma unroll
    for (int o = 0; o < 90; ++o) h[o] = fmaxf(h[o], 0.f);

    float s0=0.f,s1=0.f,s2=0.f,q0=0.f,q1=0.f,q2=0.f;
#pragma unroll 1
    for (int o = 0; o < 30; ++o) {
        const float* wr = W2C + o*32;
        float res0 = xl[o], res1 = xl[30+o], res2 = xl[60+o];
        float bo = b2v[o];
        float a0=0.f,a1=0.f,a2=0.f,a3=0.f,a4=0.f,a5=0.f;
#pragma unroll
        for (int i = 0; i < 15; ++i) {
            float wA = wr[i], wB = wr[15+i];
            a0 = fmaf(h[i],    wA, a0);  a1 = fmaf(h[15+i], wB, a1);
            a2 = fmaf(h[30+i], wA, a2);  a3 = fmaf(h[45+i], wB, a3);
            a4 = fmaf(h[60+i], wA, a4);  a5 = fmaf(h[75+i], wB, a5);
        }
        float y0 = bo + res0 + a0 + a1;
        float y1 = bo + res1 + a2 + a3;
        float y2 = bo + res2 + a4 + a5;
        xl[o] = y0; xl[30+o] = y1; xl[60+o] = y2;
        s0 += y0; s1 += y1; s2 += y2;
        q0 = fmaf(y0,y0,q0); q1 = fmaf(y1,y1,q1); q2 = fmaf(y2,y2,q2);
    }
    const float inv30 = 1.f/30.f;
    m[0]=s0*inv30; m[1]=s1*inv30; m[2]=s2*inv30;
    r[0]=rsqrtf(q0*inv30 - m[0]*m[0] + EPS);
    r[1]=rsqrtf(q1*inv30 - m[1]*m[1] + EPS);
    r[2]=rsqrtf(q2*inv30 - m[2]*m[2] + EPS);
}

// PFF90. Input xl holds RAW stage-4 output; (m4,r4) + g_pff/b_pff applied on read.
// Output RAW to xl; (m5, r5) returned.
__device__ __forceinline__ void pff90(float* xl,
    const float* m4, const float* r4,
    const float* gp, const float* bp,
    const float* W1PT, const float* W2PC, const float* b1pv, const float* b2pv,
    float& m5, float& r5)
{
    float h[90];
#pragma unroll
    for (int o = 0; o < 90; ++o) h[o] = b1pv[o];
#pragma unroll 2
    for (int i0 = 0; i0 < 30; ++i0) {
        float gi = gp[i0], bi = bp[i0];
        float x0 = fmaf((xl[i0]    - m4[0]) * r4[0], gi, bi);
        float x1 = fmaf((xl[30+i0] - m4[1]) * r4[1], gi, bi);
        float x2 = fmaf((xl[60+i0] - m4[2]) * r4[2], gi, bi);
        const float* wA = W1PT + i0*92;
        const float* wB = W1PT + (30+i0)*92;
        const float* wC = W1PT + (60+i0)*92;
#pragma unroll
        for (int o = 0; o < 90; ++o)
            h[o] = fmaf(x0, wA[o], fmaf(x1, wB[o], fmaf(x2, wC[o], h[o])));
    }
#pragma unroll
    for (int o = 0; o < 90; ++o) h[o] = fmaxf(h[o], 0.f);

    float s = 0.f, qq = 0.f;
#pragma unroll 1
    for (int o0 = 0; o0 < 30; ++o0) {
        float go = gp[o0], bo = bp[o0];
#pragma unroll
        for (int br = 0; br < 3; ++br) {
            int o = br*30 + o0;
            const float* wr = W2PC + o*92;
            float resid = fmaf((xl[o] - m4[br]) * r4[br], go, bo);
            float a0=0.f,a1=0.f,a2=0.f;
#pragma unroll
            for (int i = 0; i < 30; ++i) {
                a0 = fmaf(h[i],    wr[i],    a0);
                a1 = fmaf(h[30+i], wr[30+i], a1);
                a2 = fmaf(h[60+i], wr[60+i], a2);
            }
            float y = b2pv[o] + resid + a0 + a1 + a2;
            xl[o] = y; s += y; qq = fmaf(y, y, qq);
        }
    }
    const float inv90 = 1.f/90.f;
    m5 = s * inv90;
    r5 = rsqrtf(qq * inv90 - m5*m5 + EPS);
}

__global__ __launch_bounds__(THREADS) void moct_kernel(
    const float* __restrict__ q, const float* __restrict__ k, const float* __restrict__ v,
    const float* __restrict__ g_mha, const float* __restrict__ b_mha,
    const float* __restrict__ b1, const float* __restrict__ b2,
    const float* __restrict__ g_pff, const float* __restrict__ b_pff,
    const float* __restrict__ b1p, const float* __restrict__ b2p,
    const float* __restrict__ g_pff1, const float* __restrict__ b_pff1,
    const float* __restrict__ bc1, const float* __restrict__ Wc2, const float* __restrict__ bc2,
    const float* __restrict__ ws,
    float* __restrict__ out, int nrows, int zero)
{
    __shared__ float xbuf[THREADS * XSTRIDE];
    const int row = blockIdx.x * THREADS + threadIdx.x;
    if (row >= nrows) return;                 // no __syncthreads anywhere: safe
    float* xl = xbuf + threadIdx.x * XSTRIDE;

    // zero==0 at runtime, but divergent-typed: forces VMEM (vmcnt) instead of
    // s_load (lgkmcnt) for all weight/bias streams, so ds_read waits stay
    // fine-grained instead of draining the SMEM queue.
    const int dz = zero * (int)threadIdx.x;
    const float* wsv  = ws + dz;
    const float* W1T  = wsv + W1T_OFF;
    const float* W2C  = wsv + W2C_OFF;
    const float* W1PT = wsv + W1PT_OFF;
    const float* W2PC = wsv + W2PC_OFF;
    const float* WC1T = wsv + WC1T_OFF;
    const float* Wqv  = wsv + WQC_OFF;
    const float* Wkv  = wsv + WKC_OFF;
    const float* Wvv  = wsv + WVC_OFF;
    const float* gmv  = g_mha + dz;  const float* bmv  = b_mha + dz;
    const float* b1v  = b1 + dz;     const float* b2v  = b2 + dz;
    const float* gpv  = g_pff + dz;  const float* bpv  = b_pff + dz;
    const float* b1pv = b1p + dz;    const float* b2pv = b2p + dz;
    const float* g1v  = g_pff1 + dz; const float* bb1v = b_pff1 + dz;
    const float* bc1v = bc1 + dz;    const float* Wc2v = Wc2 + dz;
    const float* bc2v = bc2 + dz;

    const size_t rbase = (size_t)row * 90;

    // ---- stage 1: MHA(q,k,v) -> LN'd x[90] in LDS ----
#pragma unroll 1
    for (int br = 0; br < 3; ++br) {
        float qb[30], kb[30], vb[30];
        const float2* qp = (const float2*)(q + rbase + br*30);
        const float2* kp = (const float2*)(k + rbase + br*30);
        const float2* vp = (const float2*)(v + rbase + br*30);
#pragma unroll
        for (int j = 0; j < 15; ++j) {
            float2 t0 = qp[j]; qb[2*j] = t0.x; qb[2*j+1] = t0.y;
            float2 t1 = kp[j]; kb[2*j] = t1.x; kb[2*j+1] = t1.y;
            float2 t2 = vp[j]; vb[2*j] = t2.x; vb[2*j+1] = t2.y;
        }
        mha_core(qb, kb, vb, Wqv, Wkv, Wvv, gmv, bmv, xl + br*30);
    }

    // ---- stage 2: PFF30 x3 (raw out + LN params) ----
    float m2[3], r2[3];
    pff30x3(xl, W1T, W2C, b1v, b2v, m2, r2);

    // ---- stage 3: MHA(x,x,x); stage-2 LN applied on read ----
#pragma unroll 1
    for (int br = 0; br < 3; ++br) {
        float xb[30];
        float mm = m2[br], rr = r2[br];
#pragma unroll
        for (int j = 0; j < 30; ++j)
            xb[j] = fmaf((xl[br*30 + j] - mm) * rr, gpv[j], bpv[j]);
        mha_core(xb, xb, xb, Wqv, Wkv, Wvv, gmv, bmv, xl + br*30);
    }

    // ---- stage 4: PFF30 x3 (raw out + LN params) ----
    float m4[3], r4[3];
    pff30x3(xl, W1T, W2C, b1v, b2v, m4, r4);

    // ---- stage 5: PFF90; stage-4 LN fused on read; raw out + (m5,r5) ----
    float m5, r5;
    pff90(xl, m4, r4, gpv, bpv, W1PT, W2PC, b1pv, b2pv, m5, r5);

    // ---- classifier; PFF90 LN fused on read ----
    float c1[45];
#pragma unroll
    for (int o = 0; o < 45; ++o) c1[o] = bc1v[o];
#pragma unroll 2
    for (int i = 0; i < 90; ++i) {
        float xi = fmaf((xl[i] - m5) * r5, g1v[i], bb1v[i]);
        const float* wr = WC1T + i*48;
#pragma unroll
        for (int o = 0; o < 45; ++o) c1[o] = fmaf(xi, wr[o], c1[o]);
    }
#pragma unroll
    for (int o = 0; o < 45; ++o) c1[o] = fmaxf(c1[o], 0.f);

    float lg[3];
#pragma unroll
    for (int c = 0; c < 3; ++c) {
        const float* wr = Wc2v + c*45;
        float a0=0.f, a1=0.f, a2=0.f;
#pragma unroll
        for (int i = 0; i < 15; ++i) {
            a0 = fmaf(c1[i],    wr[i],    a0);
            a1 = fmaf(c1[15+i], wr[15+i], a1);
            a2 = fmaf(c1[30+i], wr[30+i], a2);
        }
        lg[c] = bc2v[c] + a0 + a1 + a2;
    }
    float mx = fmaxf(lg[0], fmaxf(lg[1], lg[2]));
    float e0 = __expf(lg[0]-mx), e1 = __expf(lg[1]-mx), e2 = __expf(lg[2]-mx);
    float inv = 1.f / (e0 + e1 + e2);
    out[row*3+0] = e0*inv;
    out[row*3+1] = e1*inv;
    out[row*3+2] = e2*inv;
}

extern "C" void kernel_launch(void* const* d_in, const int* in_sizes, int n_in,
                              void* d_out, int out_size, void* d_ws, size_t ws_size,
                              hipStream_t stream)
{
    const float* q     = (const float*)d_in[0];
    const float* k     = (const float*)d_in[1];
    const float* v     = (const float*)d_in[2];
    const float* Wq    = (const float*)d_in[3];
    const float* Wk    = (const float*)d_in[4];
    const float* Wv    = (const float*)d_in[5];
    const float* g_mha = (const float*)d_in[6];
    const float* b_mha = (const float*)d_in[7];
    const float* W1    = (const float*)d_in[8];
    const float* b1    = (const float*)d_in[9];
    const float* W2    = (const float*)d_in[10];
    const float* b2    = (const float*)d_in[11];
    const float* g_pff = (const float*)d_in[12];
    const float* b_pff = (const float*)d_in[13];
    const float* W1p   = (const float*)d_in[14];
    const float* b1p   = (const float*)d_in[15];
    const float* W2p   = (const float*)d_in[16];
    const float* b2p   = (const float*)d_in[17];
    const float* g_pff1= (const float*)d_in[18];
    const float* b_pff1= (const float*)d_in[19];
    const float* Wc1   = (const float*)d_in[20];
    const float* bc1   = (const float*)d_in[21];
    const float* Wc2   = (const float*)d_in[22];
    const float* bc2   = (const float*)d_in[23];

    float* ws = (float*)d_ws;
    const int nrows = in_sizes[0] / 90;
    volatile int zero_host = 0;   // runtime zero the device compiler can't fold

    hipLaunchKernelGGL(prep_kernel, dim3(96), dim3(256), 0, stream,
                       W1, W2, W1p, W2p, Wc1, Wq, Wk, Wv, ws);

    const int grid = (nrows + THREADS - 1) / THREADS;
    hipLaunchKernelGGL(moct_kernel, dim3(grid), dim3(THREADS), 0, stream,
        q, k, v, g_mha, b_mha,
        b1, b2, g_pff, b_pff,
        b1p, b2p, g_pff1, b_pff1,
        bc1, Wc2, bc2, ws, (float*)d_out, nrows, (int)zero_host);
}

// Round 3
// 316.382 us; speedup vs baseline: 2.8506x; 2.3192x over previous
//
#include <hip/hip_runtime.h>

#define EPS 1e-6f
#define INV_TEMP 0.31622776601683794f   // 1/sqrt(10), folded into Wq fragments

typedef float f32x4 __attribute__((ext_vector_type(4)));
typedef short short8v __attribute__((ext_vector_type(8)));

#define MFMA(a,b,c) __builtin_amdgcn_mfma_f32_16x16x32_bf16(a,b,c,0,0,0)

// ---------- B-fragment table in d_ws (bf16 shorts), 52 frags x 512 shorts ----------
// f=0..2: Wq(scaled),Wk,Wv (K=10,N=10)   f=3,4: W1 nt0,1 (K=30,N=30)
// f=5,6: W2 nt0,1                        f=7+kt*6+nt  : W1p (K=90,N=90)
// f=25+kt*6+nt: W2p                      f=43+kt*3+nt : Wc1 (K=90,N=45)
#define NFRAG 52

// ---------- LDS layout (offsets in shorts) ----------
// R1: projA [48 x 40] (stage1/3 MFMA-A input)  OR  x90 [16 x 104] (stage4+)
// X30: [48 x 40] branch-major rows (br*16 + r), feats s*10+d; shorts 30,31 = 0
// QH/KH/VH: [48 x 20] proj outputs (stage1/3); same region reused as H30/H90/C1
// RES: [48 x 12] stage-1 residual (original q, bf16)
#define R1   0
#define X30  1920
#define QH   3840
#define KH   4800
#define VH   5760
#define H30  3840
#define H90  3840
#define C1T  3840
#define RES  6720
#define SMTOT 7296          // shorts = 14592 bytes

#define S_PROJ 40           // 80 B rows: 16B-aligned, 2-way banks (free)
#define S_X90  104          // 208 B rows: 16B-aligned, 2-way banks
#define S_QH   20
#define S_RES  12
#define S_C1   48

__device__ __forceinline__ unsigned short f2b(float x){       // f32 -> bf16 RNE
  unsigned u = __float_as_uint(x);
  u += 0x7fffu + ((u>>16)&1u);
  return (unsigned short)(u>>16);
}
__device__ __forceinline__ float b2f(unsigned u16){           // low 16 bits -> f32
  return __uint_as_float(u16<<16);
}
__device__ __forceinline__ short8v ldB(const unsigned short* __restrict__ wf, int f){
  return *(const short8v*)(wf + f*512 + threadIdx.x*8);       // 16B/lane, coalesced
}
__device__ __forceinline__ short8v ldA(const unsigned short* sm, int rowbase, int stride, int koff){
  return *(const short8v*)(sm + (rowbase + (threadIdx.x&15))*stride + koff + (threadIdx.x>>4)*8);
}
__device__ __forceinline__ float qsum16(float v){             // sum across 16-lane quad
  v += __shfl_xor(v,1,64); v += __shfl_xor(v,2,64);
  v += __shfl_xor(v,4,64); v += __shfl_xor(v,8,64);
  return v;
}

// ---------------- prep: bake weights into B-fragment order ----------------
__global__ void prep_kernel(const float* __restrict__ Wq, const float* __restrict__ Wk,
                            const float* __restrict__ Wv, const float* __restrict__ W1,
                            const float* __restrict__ W2, const float* __restrict__ W1p,
                            const float* __restrict__ W2p, const float* __restrict__ Wc1,
                            unsigned short* __restrict__ wf)
{
  int t = blockIdx.x*blockDim.x + threadIdx.x;
  if (t >= NFRAG*512) return;
  int f = t>>9, e = t&511, lane = e>>3, j = e&7;
  int n = lane&15, kk = (lane>>4)*8 + j;
  const float* src; int K, N, kt, nt; float scale = 1.f;
  if (f < 3)      { src = (f==0)?Wq:(f==1)?Wk:Wv; K=10; N=10; kt=0; nt=0; if (f==0) scale=INV_TEMP; }
  else if (f < 5) { src = W1;  K=30; N=30; kt=0; nt=f-3; }
  else if (f < 7) { src = W2;  K=30; N=30; kt=0; nt=f-5; }
  else if (f < 25){ int g=f-7;  src = W1p; K=90; N=90; kt=g/6; nt=g%6; }
  else if (f < 43){ int g=f-25; src = W2p; K=90; N=90; kt=g/6; nt=g%6; }
  else            { int g=f-43; src = Wc1; K=90; N=45; kt=g/3; nt=g%3; }
  int gn = nt*16 + n, gk = kt*32 + kk;
  float v = (gn < N && gk < K) ? src[gn*K + gk]*scale : 0.f;   // B[k][n] = W[n][k]
  wf[t] = f2b(v);
}

// ---------------- per-branch attention (VALU, lanes 0..47) ----------------
__device__ __forceinline__ void attn_phase(unsigned short* sm, int b, bool s1,
    const float* __restrict__ g, const float* __restrict__ bb)
{
  int l = threadIdx.x;
  if (l >= 48) return;
  int r = l/3, s = l - r*3;
  float qv[10], ov[10], at[3];
  { const unsigned* p = (const unsigned*)(sm + QH + l*S_QH);
    #pragma unroll
    for (int e=0;e<5;++e){ unsigned u=p[e]; qv[2*e]=b2f(u&0xffffu); qv[2*e+1]=b2f(u>>16); } }
  #pragma unroll
  for (int t=0;t<3;++t){
    const unsigned* p = (const unsigned*)(sm + KH + (r*3+t)*S_QH);
    float a = 0.f;
    #pragma unroll
    for (int e=0;e<5;++e){ unsigned u=p[e];
      a = fmaf(qv[2*e],   b2f(u&0xffffu), a);
      a = fmaf(qv[2*e+1], b2f(u>>16),    a); }
    at[t] = a;                                  // qh pre-scaled by 1/sqrt(10)
  }
  { const unsigned* p = s1 ? (const unsigned*)(sm + RES + l*S_RES)
                           : (const unsigned*)(sm + X30 + (b*16+r)*S_PROJ + s*10);
    #pragma unroll
    for (int e=0;e<5;++e){ unsigned u=p[e]; ov[2*e]=b2f(u&0xffffu); ov[2*e+1]=b2f(u>>16); } }
  #pragma unroll
  for (int t=0;t<3;++t){
    const unsigned* p = (const unsigned*)(sm + VH + (r*3+t)*S_QH);
    #pragma unroll
    for (int e=0;e<5;++e){ unsigned u=p[e];
      ov[2*e]   = fmaf(at[t], b2f(u&0xffffu), ov[2*e]);
      ov[2*e+1] = fmaf(at[t], b2f(u>>16),    ov[2*e+1]); }
  }
  float sum=0.f, sq=0.f;
  #pragma unroll
  for (int d=0;d<10;++d){ sum += ov[d]; sq = fmaf(ov[d],ov[d],sq); }
  float mm = sum*0.1f, rs = rsqrtf(sq*0.1f - mm*mm + EPS);
  unsigned short* wp = sm + X30 + (b*16+r)*S_PROJ + s*10;
  #pragma unroll
  for (int d=0;d<10;++d) wp[d] = f2b(fmaf((ov[d]-mm)*rs, g[d], bb[d]));
  if (s==0) *(unsigned*)(sm + X30 + (b*16+r)*S_PROJ + 30) = 0u;  // keep k-pad zero
}

// ---------------- PFF30 on all 48 branch-rows (2 MFMA layers + fused LN) ----------------
template<bool TO_X90>
__device__ __forceinline__ void pff30(unsigned short* sm, const unsigned short* __restrict__ wf,
  const float* __restrict__ b1, const float* __restrict__ b2,
  const float* __restrict__ g, const float* __restrict__ bb)
{
  const int m15 = threadIdx.x & 15, quad = threadIdx.x >> 4;
  const bool c1ok = (m15 < 14);                 // col 16+m15 < 30
  float bi0 = b1[m15], bi1 = c1ok ? b1[16+m15] : 0.f;
  float b20 = b2[m15], b21 = c1ok ? b2[16+m15] : 0.f;
  float g0  = g[m15],  g1  = c1ok ? g[16+m15]  : 0.f;
  float e0  = bb[m15], e1  = c1ok ? bb[16+m15] : 0.f;
  short8v B10 = ldB(wf,3), B11 = ldB(wf,4), B20 = ldB(wf,5), B21 = ldB(wf,6);
  #pragma unroll 1
  for (int mt=0; mt<3; ++mt){
    short8v A = ldA(sm + X30, mt*16, S_PROJ, 0);
    f32x4 C0 = {0.f,0.f,0.f,0.f}, C1 = {0.f,0.f,0.f,0.f};
    C0 = MFMA(A, B10, C0);
    C1 = MFMA(A, B11, C1);
    #pragma unroll
    for (int rg=0; rg<4; ++rg){
      int row = mt*16 + quad*4 + rg;
      sm[H30 + row*S_PROJ + m15]    = f2b(fmaxf(C0[rg]+bi0, 0.f));
      sm[H30 + row*S_PROJ + 16+m15] = f2b(fmaxf(C1[rg]+bi1, 0.f));  // cols 30,31 = 0
    }
    short8v A2 = ldA(sm + H30, mt*16, S_PROJ, 0);
    f32x4 D0 = {0.f,0.f,0.f,0.f}, D1 = {0.f,0.f,0.f,0.f};
    D0 = MFMA(A2, B20, D0);
    D1 = MFMA(A2, B21, D1);
    float y0[4], y1[4];
    #pragma unroll
    for (int rg=0; rg<4; ++rg){
      int row = mt*16 + quad*4 + rg;
      float r0 = b2f(sm[X30 + row*S_PROJ + m15]);
      float r1 = c1ok ? b2f(sm[X30 + row*S_PROJ + 16+m15]) : 0.f;
      y0[rg] = D0[rg] + b20 + r0;
      y1[rg] = c1ok ? (D1[rg] + b21 + r1) : 0.f;
    }
    #pragma unroll
    for (int rg=0; rg<4; ++rg){
      float sr = qsum16(y0[rg] + y1[rg]);
      float qr = qsum16(y0[rg]*y0[rg] + y1[rg]*y1[rg]);
      float mm = sr * (1.f/30.f);
      float rs = rsqrtf(qr*(1.f/30.f) - mm*mm + EPS);
      float z0 = fmaf((y0[rg]-mm)*rs, g0, e0);
      float z1 = fmaf((y1[rg]-mm)*rs, g1, e1);
      int row = mt*16 + quad*4 + rg;
      if (!TO_X90){
        sm[X30 + row*S_PROJ + m15] = f2b(z0);
        if (c1ok) sm[X30 + row*S_PROJ + 16+m15] = f2b(z1);   // cols 30,31 stay 0
      } else {
        int rr = quad*4 + rg;                                 // brow = mt*16+rr -> x90[rr][mt*30+col]
        sm[R1 + rr*S_X90 + mt*30 + m15] = f2b(z0);
        if (c1ok) sm[R1 + rr*S_X90 + mt*30 + 16+m15] = f2b(z1);
      }
    }
  }
}

// ---------------- PFF90 on x90 [16 x 90] ----------------
__device__ __forceinline__ void pff90(unsigned short* sm, const unsigned short* __restrict__ wf,
  const float* __restrict__ b1p, const float* __restrict__ b2p,
  const float* __restrict__ g1, const float* __restrict__ bb1)
{
  const int m15 = threadIdx.x & 15, quad = threadIdx.x >> 4;
  short8v A0 = ldA(sm+R1, 0, S_X90, 0);
  short8v A1 = ldA(sm+R1, 0, S_X90, 32);
  short8v A2 = ldA(sm+R1, 0, S_X90, 64);
  #pragma unroll
  for (int nt=0; nt<6; ++nt){
    f32x4 c = {0.f,0.f,0.f,0.f};
    c = MFMA(A0, ldB(wf, 7+nt),    c);
    c = MFMA(A1, ldB(wf, 13+nt),   c);
    c = MFMA(A2, ldB(wf, 19+nt),   c);
    int col = nt*16 + m15;
    float bi = (col < 90) ? b1p[col] : 0.f;
    #pragma unroll
    for (int rg=0; rg<4; ++rg)
      sm[H90 + (quad*4+rg)*S_X90 + col] = f2b(fmaxf(c[rg]+bi, 0.f));  // cols>=90 -> 0
  }
  short8v H0 = ldA(sm+H90, 0, S_X90, 0);
  short8v H1 = ldA(sm+H90, 0, S_X90, 32);
  short8v H2 = ldA(sm+H90, 0, S_X90, 64);
  float y[6][4];
  #pragma unroll
  for (int nt=0; nt<6; ++nt){
    f32x4 d = {0.f,0.f,0.f,0.f};
    d = MFMA(H0, ldB(wf, 25+nt), d);
    d = MFMA(H1, ldB(wf, 31+nt), d);
    d = MFMA(H2, ldB(wf, 37+nt), d);
    int col = nt*16 + m15;
    bool ok = (col < 90);
    float b2v = ok ? b2p[col] : 0.f;
    #pragma unroll
    for (int rg=0; rg<4; ++rg){
      float rv = ok ? b2f(sm[R1 + (quad*4+rg)*S_X90 + col]) : 0.f;
      y[nt][rg] = ok ? (d[rg] + b2v + rv) : 0.f;
    }
  }
  #pragma unroll
  for (int rg=0; rg<4; ++rg){
    float ps = 0.f, pq = 0.f;
    #pragma unroll
    for (int nt=0; nt<6; ++nt){ ps += y[nt][rg]; pq = fmaf(y[nt][rg], y[nt][rg], pq); }
    float sr = qsum16(ps), qr = qsum16(pq);
    float mm = sr*(1.f/90.f);
    float rs = rsqrtf(qr*(1.f/90.f) - mm*mm + EPS);
    int row = quad*4 + rg;
    #pragma unroll
    for (int nt=0; nt<6; ++nt){
      int col = nt*16 + m15;
      if (col < 90)
        sm[R1 + row*S_X90 + col] = f2b(fmaf((y[nt][rg]-mm)*rs, g1[col], bb1[col]));
    }
  }
}

// ---------------- classifier + softmax ----------------
__device__ __forceinline__ void classifier(unsigned short* sm, const unsigned short* __restrict__ wf,
  const float* __restrict__ bc1, const float* __restrict__ Wc2, const float* __restrict__ bc2,
  float* __restrict__ out, int row0)
{
  const int m15 = threadIdx.x & 15, quad = threadIdx.x >> 4;
  short8v A0 = ldA(sm+R1, 0, S_X90, 0);
  short8v A1 = ldA(sm+R1, 0, S_X90, 32);
  short8v A2 = ldA(sm+R1, 0, S_X90, 64);
  #pragma unroll
  for (int nt=0; nt<3; ++nt){
    f32x4 c = {0.f,0.f,0.f,0.f};
    c = MFMA(A0, ldB(wf, 43+nt), c);
    c = MFMA(A1, ldB(wf, 46+nt), c);
    c = MFMA(A2, ldB(wf, 49+nt), c);
    int col = nt*16 + m15;
    float bi = (col < 45) ? bc1[col] : 0.f;
    #pragma unroll
    for (int rg=0; rg<4; ++rg)
      sm[C1T + (quad*4+rg)*S_C1 + col] = f2b(fmaxf(c[rg]+bi, 0.f));
  }
  int row = m15, p = quad;
  int i0 = p*12, cnt = (p<3) ? 12 : 9;
  float lg0=0.f, lg1=0.f, lg2=0.f;
  for (int ii=0; ii<cnt; ++ii){
    float cv = b2f(sm[C1T + row*S_C1 + i0+ii]);
    lg0 = fmaf(cv, Wc2[     i0+ii], lg0);
    lg1 = fmaf(cv, Wc2[45 + i0+ii], lg1);
    lg2 = fmaf(cv, Wc2[90 + i0+ii], lg2);
  }
  lg0 += __shfl_xor(lg0,16,64); lg0 += __shfl_xor(lg0,32,64);
  lg1 += __shfl_xor(lg1,16,64); lg1 += __shfl_xor(lg1,32,64);
  lg2 += __shfl_xor(lg2,16,64); lg2 += __shfl_xor(lg2,32,64);
  lg0 += bc2[0]; lg1 += bc2[1]; lg2 += bc2[2];
  float mx = fmaxf(lg0, fmaxf(lg1,lg2));
  float x0 = __expf(lg0-mx), x1 = __expf(lg1-mx), x2 = __expf(lg2-mx);
  float inv = 1.f/(x0+x1+x2);
  if (p == 0){
    float* o = out + (size_t)(row0+row)*3;
    o[0]=x0*inv; o[1]=x1*inv; o[2]=x2*inv;
  }
}

// ---------------- main: one wave = 16 rows, wave-synchronous ----------------
__global__ __launch_bounds__(64) void moct_kernel(
  const float* __restrict__ q, const float* __restrict__ k, const float* __restrict__ v,
  const float* __restrict__ g_mha, const float* __restrict__ b_mha,
  const float* __restrict__ b1, const float* __restrict__ b2,
  const float* __restrict__ g_pff, const float* __restrict__ b_pff,
  const float* __restrict__ b1p, const float* __restrict__ b2p,
  const float* __restrict__ g_pff1, const float* __restrict__ b_pff1,
  const float* __restrict__ bc1, const float* __restrict__ Wc2, const float* __restrict__ bc2,
  const unsigned short* __restrict__ wf,
  float* __restrict__ out)
{
  __shared__ __align__(16) unsigned short sm[SMTOT];
  const int tid = threadIdx.x;
  const int m15 = tid & 15, quad = tid >> 4;
  const int row0 = blockIdx.x * 16;

  { // prezero projA (k-pad must be 0) + x30 (shorts 30,31)
    unsigned* pw = (unsigned*)sm;
    #pragma unroll
    for (int i=0; i<30; ++i) pw[tid + i*64] = 0u;   // words 0..1919 = R1+X30
  }

  // ---- stage 1: MHA(q,k,v) ----
  #pragma unroll 1
  for (int b=0; b<3; ++b){
    #pragma unroll 1
    for (int w=0; w<3; ++w){
      const float* T = (w==0) ? q : (w==1) ? k : v;
      { // stage 16 rows x 30 floats of branch b into projA (bf16, feats 0..9 per seq)
        int rl = tid >> 2, part = tid & 3;
        const float2* s2 = (const float2*)(T + (size_t)(row0+rl)*90 + b*30 + part*8);
        float vals[8];
        float2 t0 = s2[0], t1 = s2[1], t2 = s2[2];
        vals[0]=t0.x; vals[1]=t0.y; vals[2]=t1.x; vals[3]=t1.y; vals[4]=t2.x; vals[5]=t2.y;
        vals[6]=0.f;  vals[7]=0.f;
        if (part < 3){ float2 t3 = s2[3]; vals[6]=t3.x; vals[7]=t3.y; }
        int cnt = (part==3) ? 6 : 8;
        for (int e=0; e<cnt; ++e){
          int f = part*8 + e;
          int s = (f>=20) ? 2 : ((f>=10) ? 1 : 0);
          int d = f - s*10;
          int sr = rl*3 + s;
          unsigned short hv = f2b(vals[e]);
          sm[R1 + sr*S_PROJ + d] = hv;
          if (w == 0) sm[RES + sr*S_RES + d] = hv;   // stage-1 residual = q
        }
      }
      short8v B = ldB(wf, w);
      int dst = QH + w*960;
      #pragma unroll
      for (int mt=0; mt<3; ++mt){
        short8v A = ldA(sm+R1, mt*16, S_PROJ, 0);
        f32x4 c = {0.f,0.f,0.f,0.f};
        c = MFMA(A, B, c);
        #pragma unroll
        for (int rg=0; rg<4; ++rg)
          sm[dst + (mt*16+quad*4+rg)*S_QH + m15] = f2b(c[rg]);
      }
    }
    attn_phase(sm, b, true, g_mha, b_mha);
  }

  // ---- stage 2: PFF30 (in-place x30) ----
  pff30<false>(sm, wf, b1, b2, g_pff, b_pff);

  // ---- stage 3: MHA(x,x,x) ----
  #pragma unroll 1
  for (int b=0; b<3; ++b){
    if (tid < 48){   // repack x30 branch b -> projA seq-rows (k-pad zeros persist)
      int r = tid/3, s = tid - r*3;
      const unsigned* sp = (const unsigned*)(sm + X30 + (b*16+r)*S_PROJ + s*10);
      unsigned* dp = (unsigned*)(sm + R1 + tid*S_PROJ);
      #pragma unroll
      for (int e=0; e<5; ++e) dp[e] = sp[e];
    }
    short8v B0 = ldB(wf,0), B1 = ldB(wf,1), B2 = ldB(wf,2);
    #pragma unroll
    for (int mt=0; mt<3; ++mt){
      short8v A = ldA(sm+R1, mt*16, S_PROJ, 0);
      f32x4 c0={0.f,0.f,0.f,0.f}, c1={0.f,0.f,0.f,0.f}, c2={0.f,0.f,0.f,0.f};
      c0 = MFMA(A,B0,c0); c1 = MFMA(A,B1,c1); c2 = MFMA(A,B2,c2);
      #pragma unroll
      for (int rg=0; rg<4; ++rg){
        int rw = mt*16 + quad*4 + rg;
        sm[QH + rw*S_QH + m15] = f2b(c0[rg]);
        sm[KH + rw*S_QH + m15] = f2b(c1[rg]);
        sm[VH + rw*S_QH + m15] = f2b(c2[rg]);
      }
    }
    attn_phase(sm, b, false, g_mha, b_mha);
  }

  { // zero x90 pad (shorts 90..103 of each of 16 rows = words 45..51, stride 52)
    int i = tid;
    #pragma unroll
    for (int t=0; t<2; ++t){
      if (i < 112){
        int rr = i/7, wd = i - rr*7;
        ((unsigned*)(sm + R1))[rr*52 + 45 + wd] = 0u;
      }
      i += 64;
    }
  }

  // ---- stage 4: PFF30 -> x90 ----
  pff30<true>(sm, wf, b1, b2, g_pff, b_pff);
  // ---- stage 5: PFF90 (in-place x90) ----
  pff90(sm, wf, b1p, b2p, g_pff1, b_pff1);
  // ---- classifier + softmax ----
  classifier(sm, wf, bc1, Wc2, bc2, out, row0);
}

extern "C" void kernel_launch(void* const* d_in, const int* in_sizes, int n_in,
                              void* d_out, int out_size, void* d_ws, size_t ws_size,
                              hipStream_t stream)
{
  const float* q     = (const float*)d_in[0];
  const float* k     = (const float*)d_in[1];
  const float* v     = (const float*)d_in[2];
  const float* Wq    = (const float*)d_in[3];
  const float* Wk    = (const float*)d_in[4];
  const float* Wv    = (const float*)d_in[5];
  const float* g_mha = (const float*)d_in[6];
  const float* b_mha = (const float*)d_in[7];
  const float* W1    = (const float*)d_in[8];
  const float* b1    = (const float*)d_in[9];
  const float* W2    = (const float*)d_in[10];
  const float* b2    = (const float*)d_in[11];
  const float* g_pff = (const float*)d_in[12];
  const float* b_pff = (const float*)d_in[13];
  const float* W1p   = (const float*)d_in[14];
  const float* b1p   = (const float*)d_in[15];
  const float* W2p   = (const float*)d_in[16];
  const float* b2p   = (const float*)d_in[17];
  const float* g_pff1= (const float*)d_in[18];
  const float* b_pff1= (const float*)d_in[19];
  const float* Wc1   = (const float*)d_in[20];
  const float* bc1   = (const float*)d_in[21];
  const float* Wc2   = (const float*)d_in[22];
  const float* bc2   = (const float*)d_in[23];

  unsigned short* wf = (unsigned short*)d_ws;
  const int nrows = in_sizes[0] / 90;

  hipLaunchKernelGGL(prep_kernel, dim3((NFRAG*512 + 255)/256), dim3(256), 0, stream,
                     Wq, Wk, Wv, W1, W2, W1p, W2p, Wc1, wf);

  hipLaunchKernelGGL(moct_kernel, dim3(nrows/16), dim3(64), 0, stream,
    q, k, v, g_mha, b_mha, b1, b2, g_pff, b_pff,
    b1p, b2p, g_pff1, b_pff1, bc1, Wc2, bc2, wf, (float*)d_out);
}

// Round 5
// 313.471 us; speedup vs baseline: 2.8770x; 1.0093x over previous
//
#include <hip/hip_runtime.h>
#include <hip/hip_bf16.h>

#define EPS 1e-6f
#define INV_TEMP 0.31622776601683794f   // 1/sqrt(10), folded into Wq fragments

typedef float f32x4 __attribute__((ext_vector_type(4)));
typedef short short8v __attribute__((ext_vector_type(8)));
typedef unsigned uint4v __attribute__((ext_vector_type(4)));

#define MFMA(a,b,c) __builtin_amdgcn_mfma_f32_16x16x32_bf16(a,b,c,0,0,0)

// ---------- B-fragment table in d_ws (bf16 shorts), 52 frags x 512 shorts ----------
// f=0..2: Wq(scaled),Wk,Wv (K=10,N=10)   f=3,4: W1 nt0,1 (K=30,N=30)
// f=5,6: W2 nt0,1                        f=7+kt*6+nt  : W1p (K=90,N=90)
// f=25+kt*6+nt: W2p                      f=43+kt*3+nt : Wc1 (K=90,N=45)
// prep zeroes all out-of-range K/N rows -> A-fragment k-pad contributes 0
// as long as it is FINITE (pads are explicitly zeroed below for safety).
#define NFRAG 52

// ---------- per-wave LDS layout (offsets in shorts) ----------
#define X30   0        // [48 x 40] branch-major rows (b*16+r), feats s*10+d; shorts 30,31 = 0
#define PROJ  1920     // [48 x 40] stage3 A-repack; aliases H30, H90[16x104], C1T[16x48]
#define QKV   3840     // qh/kh/vh [48 x 14] x3; aliases X90 [16 x 104]
#define QH    3840
#define KH    4512
#define VH    5184
#define X90   3840
#define H30   1920
#define H90   1920
#define C1T   1920
#define WSM   5856     // shorts per wave = 11712 B (16B-multiple)

#define S_P   40       // 80 B rows (16B-aligned)
#define S_Q   14       // qkv row stride
#define S_X9  104      // 208 B rows (16B-aligned)
#define S_C1  48

// ---------------- bf16 conversion (HIP header semantics — verified-correct order) ----
__device__ __forceinline__ unsigned short f2b_sw(float x){       // RNE, host-prep use
  unsigned u = __float_as_uint(x);
  u += 0x7fffu + ((u>>16)&1u);
  return (unsigned short)(u>>16);
}
__device__ __forceinline__ unsigned pack2(float a, float b){     // low=a, high=b, RNE
  float2 t; t.x = a; t.y = b;
  __hip_bfloat162 h = __float22bfloat162_rn(t);
  unsigned u; __builtin_memcpy(&u, &h, 4); return u;
}
__device__ __forceinline__ unsigned short f2b(float x){
  __hip_bfloat16 h = __float2bfloat16(x);
  unsigned short u; __builtin_memcpy(&u, &h, 2); return u;
}
__device__ __forceinline__ float b2f(unsigned u16){              // low 16 bits -> f32
  return __uint_as_float(u16<<16);
}
__device__ __forceinline__ short8v ldB(const unsigned short* __restrict__ wf, int f, int wtid){
  return *(const short8v*)(wf + f*512 + wtid*8);                 // 16B/lane
}
__device__ __forceinline__ short8v ldA(const unsigned short* sm, int rowbase, int stride, int koff, int wtid){
  return *(const short8v*)(sm + (rowbase + (wtid&15))*stride + koff + (wtid>>4)*8);
}
__device__ __forceinline__ float qsum16(float v){                // sum across 16-lane quad
  v += __shfl_xor(v,1,64); v += __shfl_xor(v,2,64);
  v += __shfl_xor(v,4,64); v += __shfl_xor(v,8,64);
  return v;
}

// ---------------- prep: bake weights into B-fragment order ----------------
__global__ void prep_kernel(const float* __restrict__ Wq, const float* __restrict__ Wk,
                            const float* __restrict__ Wv, const float* __restrict__ W1,
                            const float* __restrict__ W2, const float* __restrict__ W1p,
                            const float* __restrict__ W2p, const float* __restrict__ Wc1,
                            unsigned short* __restrict__ wf)
{
  int t = blockIdx.x*blockDim.x + threadIdx.x;
  if (t >= NFRAG*512) return;
  int f = t>>9, e = t&511, lane = e>>3, j = e&7;
  int n = lane&15, kk = (lane>>4)*8 + j;
  const float* src; int K, N, kt, nt; float scale = 1.f;
  if (f < 3)      { src = (f==0)?Wq:(f==1)?Wk:Wv; K=10; N=10; kt=0; nt=0; if (f==0) scale=INV_TEMP; }
  else if (f < 5) { src = W1;  K=30; N=30; kt=0; nt=f-3; }
  else if (f < 7) { src = W2;  K=30; N=30; kt=0; nt=f-5; }
  else if (f < 25){ int g=f-7;  src = W1p; K=90; N=90; kt=g/6; nt=g%6; }
  else if (f < 43){ int g=f-25; src = W2p; K=90; N=90; kt=g/6; nt=g%6; }
  else            { int g=f-43; src = Wc1; K=90; N=45; kt=g/3; nt=g%3; }
  int gn = nt*16 + n, gk = kt*32 + kk;
  float v = (gn < N && gk < K) ? src[gn*K + gk]*scale : 0.f;   // B[k][n] = W[n][k]
  wf[t] = f2b_sw(v);
}

// ---------------- per-branch attention (VALU, lanes 0..47 of the wave) ----------------
template<bool S1>
__device__ __forceinline__ void attn_phase(unsigned short* sm, int wtid, int b,
    const float* res, const float* __restrict__ g, const float* __restrict__ bb)
{
  if (wtid >= 48) return;
  int r = wtid/3, s = wtid - 3*r;
  float qv[10], ov[10], at[3];
  { const unsigned* p = (const unsigned*)(sm + QH + wtid*S_Q);
    #pragma unroll
    for (int e=0;e<5;++e){ unsigned u=p[e]; qv[2*e]=b2f(u&0xffffu); qv[2*e+1]=b2f(u>>16); } }
  #pragma unroll
  for (int t=0;t<3;++t){
    const unsigned* p = (const unsigned*)(sm + KH + (r*3+t)*S_Q);
    float a = 0.f;
    #pragma unroll
    for (int e=0;e<5;++e){ unsigned u=p[e];
      a = fmaf(qv[2*e],   b2f(u&0xffffu), a);
      a = fmaf(qv[2*e+1], b2f(u>>16),    a); }
    at[t] = a;                                  // qh pre-scaled by 1/sqrt(10)
  }
  if (S1){
    #pragma unroll
    for (int d=0;d<10;++d) ov[d] = res[d];      // fp32 residual from registers
  } else {
    const unsigned* p = (const unsigned*)(sm + X30 + (b*16+r)*S_P + s*10);
    #pragma unroll
    for (int e=0;e<5;++e){ unsigned u=p[e]; ov[2*e]=b2f(u&0xffffu); ov[2*e+1]=b2f(u>>16); }
  }
  #pragma unroll
  for (int t=0;t<3;++t){
    const unsigned* p = (const unsigned*)(sm + VH + (r*3+t)*S_Q);
    #pragma unroll
    for (int e=0;e<5;++e){ unsigned u=p[e];
      ov[2*e]   = fmaf(at[t], b2f(u&0xffffu), ov[2*e]);
      ov[2*e+1] = fmaf(at[t], b2f(u>>16),    ov[2*e+1]); }
  }
  float sum=0.f, sq=0.f;
  #pragma unroll
  for (int d=0;d<10;++d){ sum += ov[d]; sq = fmaf(ov[d],ov[d],sq); }
  float mm = sum*0.1f, rs = rsqrtf(sq*0.1f - mm*mm + EPS);
  unsigned* wp = (unsigned*)(sm + X30 + (b*16+r)*S_P + s*10);
  #pragma unroll
  for (int e=0;e<5;++e){
    float z0 = fmaf((ov[2*e]-mm)*rs,   g[2*e],   bb[2*e]);
    float z1 = fmaf((ov[2*e+1]-mm)*rs, g[2*e+1], bb[2*e+1]);
    wp[e] = pack2(z0, z1);
  }
}

// ---------------- PFF30 on all 48 branch-rows ----------------
template<bool TO_X90>
__device__ __forceinline__ void pff30(unsigned short* sm, int wtid, const unsigned short* __restrict__ wf,
  const float* __restrict__ b1, const float* __restrict__ b2,
  const float* __restrict__ g, const float* __restrict__ bb)
{
  const int m15 = wtid & 15, quad = wtid >> 4;
  const bool c1ok = (m15 < 14);                 // col 16+m15 < 30
  float bi0 = b1[m15], bi1 = c1ok ? b1[16+m15] : 0.f;
  float b20 = b2[m15], b21 = c1ok ? b2[16+m15] : 0.f;
  float g0  = g[m15],  g1  = c1ok ? g[16+m15]  : 0.f;
  float e0  = bb[m15], e1  = c1ok ? bb[16+m15] : 0.f;
  short8v B10 = ldB(wf,3,wtid), B11 = ldB(wf,4,wtid), B20 = ldB(wf,5,wtid), B21 = ldB(wf,6,wtid);
  #pragma unroll 1
  for (int mt=0; mt<3; ++mt){
    short8v A = ldA(sm + X30, mt*16, S_P, 0, wtid);
    f32x4 C0 = {0.f,0.f,0.f,0.f}, C1 = {0.f,0.f,0.f,0.f};
    C0 = MFMA(A, B10, C0);
    C1 = MFMA(A, B11, C1);
    #pragma unroll
    for (int rg=0; rg<4; ++rg){
      int row = mt*16 + quad*4 + rg;
      sm[H30 + row*S_P + m15]    = f2b(fmaxf(C0[rg]+bi0, 0.f));
      sm[H30 + row*S_P + 16+m15] = f2b(fmaxf(C1[rg]+bi1, 0.f));  // cols 30,31 -> 0
    }
    short8v A2 = ldA(sm + H30, mt*16, S_P, 0, wtid);
    f32x4 D0 = {0.f,0.f,0.f,0.f}, D1 = {0.f,0.f,0.f,0.f};
    D0 = MFMA(A2, B20, D0);
    D1 = MFMA(A2, B21, D1);
    float y0[4], y1[4];
    #pragma unroll
    for (int rg=0; rg<4; ++rg){
      int row = mt*16 + quad*4 + rg;
      float r0 = b2f(sm[X30 + row*S_P + m15]);
      float r1 = c1ok ? b2f(sm[X30 + row*S_P + 16+m15]) : 0.f;
      y0[rg] = D0[rg] + b20 + r0;
      y1[rg] = c1ok ? (D1[rg] + b21 + r1) : 0.f;
    }
    #pragma unroll
    for (int rg=0; rg<4; ++rg){
      float sr = qsum16(y0[rg] + y1[rg]);
      float qr = qsum16(y0[rg]*y0[rg] + y1[rg]*y1[rg]);
      float mm = sr * (1.f/30.f);
      float rs = rsqrtf(qr*(1.f/30.f) - mm*mm + EPS);
      float z0 = fmaf((y0[rg]-mm)*rs, g0, e0);
      float z1 = fmaf((y1[rg]-mm)*rs, g1, e1);   // 0 when !c1ok
      if (!TO_X90){
        int row = mt*16 + quad*4 + rg;
        sm[X30 + row*S_P + m15]    = f2b(z0);
        sm[X30 + row*S_P + 16+m15] = f2b(z1);    // cols 30,31 stay 0
      } else {
        int rr = quad*4 + rg;                    // brow = mt*16+rr -> x90[rr][mt*30+col]
        sm[X90 + rr*S_X9 + mt*30 + m15]    = f2b(z0);
        sm[X90 + rr*S_X9 + mt*30 + 16+m15] = f2b(z1);
      }
    }
  }
}

// ---------------- PFF90 on x90 [16 x 90] ----------------
__device__ __forceinline__ void pff90(unsigned short* sm, int wtid, const unsigned short* __restrict__ wf,
  const float* __restrict__ b1p, const float* __restrict__ b2p,
  const float* __restrict__ g1, const float* __restrict__ bb1)
{
  const int m15 = wtid & 15, quad = wtid >> 4;
  short8v A0 = ldA(sm+X90, 0, S_X9, 0,  wtid);
  short8v A1 = ldA(sm+X90, 0, S_X9, 32, wtid);
  short8v A2 = ldA(sm+X90, 0, S_X9, 64, wtid);
  #pragma unroll
  for (int nt=0; nt<6; ++nt){
    f32x4 c = {0.f,0.f,0.f,0.f};
    c = MFMA(A0, ldB(wf, 7+nt,  wtid), c);
    c = MFMA(A1, ldB(wf, 13+nt, wtid), c);
    c = MFMA(A2, ldB(wf, 19+nt, wtid), c);
    int col = nt*16 + m15;
    float bi = (col < 90) ? b1p[col] : 0.f;
    #pragma unroll
    for (int rg=0; rg<4; ++rg)
      sm[H90 + (quad*4+rg)*S_X9 + col] = f2b(fmaxf(c[rg]+bi, 0.f));  // cols>=90 -> 0
  }
  short8v H0 = ldA(sm+H90, 0, S_X9, 0,  wtid);
  short8v H1 = ldA(sm+H90, 0, S_X9, 32, wtid);
  short8v H2 = ldA(sm+H90, 0, S_X9, 64, wtid);
  float y[6][4];
  #pragma unroll
  for (int nt=0; nt<6; ++nt){
    f32x4 d = {0.f,0.f,0.f,0.f};
    d = MFMA(H0, ldB(wf, 25+nt, wtid), d);
    d = MFMA(H1, ldB(wf, 31+nt, wtid), d);
    d = MFMA(H2, ldB(wf, 37+nt, wtid), d);
    int col = nt*16 + m15;
    bool ok = (col < 90);
    float b2v = ok ? b2p[col] : 0.f;
    #pragma unroll
    for (int rg=0; rg<4; ++rg){
      float rv = ok ? b2f(sm[X90 + (quad*4+rg)*S_X9 + col]) : 0.f;
      y[nt][rg] = ok ? (d[rg] + b2v + rv) : 0.f;
    }
  }
  #pragma unroll
  for (int rg=0; rg<4; ++rg){
    float ps = 0.f, pq = 0.f;
    #pragma unroll
    for (int nt=0; nt<6; ++nt){ ps += y[nt][rg]; pq = fmaf(y[nt][rg], y[nt][rg], pq); }
    float sr = qsum16(ps), qr = qsum16(pq);
    float mm = sr*(1.f/90.f);
    float rs = rsqrtf(qr*(1.f/90.f) - mm*mm + EPS);
    int row = quad*4 + rg;
    #pragma unroll
    for (int nt=0; nt<6; ++nt){
      int col = nt*16 + m15;
      if (col < 90)
        sm[X90 + row*S_X9 + col] = f2b(fmaf((y[nt][rg]-mm)*rs, g1[col], bb1[col]));
    }
  }
}

// ---------------- classifier + softmax ----------------
__device__ __forceinline__ void classifier(unsigned short* sm, int wtid, const unsigned short* __restrict__ wf,
  const float* __restrict__ bc1, const float* __restrict__ Wc2, const float* __restrict__ bc2,
  float* __restrict__ out, int row0)
{
  const int m15 = wtid & 15, quad = wtid >> 4;
  short8v A0 = ldA(sm+X90, 0, S_X9, 0,  wtid);
  short8v A1 = ldA(sm+X90, 0, S_X9, 32, wtid);
  short8v A2 = ldA(sm+X90, 0, S_X9, 64, wtid);
  #pragma unroll
  for (int nt=0; nt<3; ++nt){
    f32x4 c = {0.f,0.f,0.f,0.f};
    c = MFMA(A0, ldB(wf, 43+nt, wtid), c);
    c = MFMA(A1, ldB(wf, 46+nt, wtid), c);
    c = MFMA(A2, ldB(wf, 49+nt, wtid), c);
    int col = nt*16 + m15;
    float bi = (col < 45) ? bc1[col] : 0.f;
    #pragma unroll
    for (int rg=0; rg<4; ++rg)
      sm[C1T + (quad*4+rg)*S_C1 + col] = f2b(fmaxf(c[rg]+bi, 0.f));
  }
  int row = m15, p = quad;
  int i0 = p*12, cnt = (p<3) ? 12 : 9;
  float lg0=0.f, lg1=0.f, lg2=0.f;
  for (int ii=0; ii<cnt; ++ii){
    float cv = b2f(sm[C1T + row*S_C1 + i0+ii]);
    lg0 = fmaf(cv, Wc2[     i0+ii], lg0);
    lg1 = fmaf(cv, Wc2[45 + i0+ii], lg1);
    lg2 = fmaf(cv, Wc2[90 + i0+ii], lg2);
  }
  lg0 += __shfl_xor(lg0,16,64); lg0 += __shfl_xor(lg0,32,64);
  lg1 += __shfl_xor(lg1,16,64); lg1 += __shfl_xor(lg1,32,64);
  lg2 += __shfl_xor(lg2,16,64); lg2 += __shfl_xor(lg2,32,64);
  lg0 += bc2[0]; lg1 += bc2[1]; lg2 += bc2[2];
  float mx = fmaxf(lg0, fmaxf(lg1,lg2));
  float x0 = __expf(lg0-mx), x1 = __expf(lg1-mx), x2 = __expf(lg2-mx);
  float inv = 1.f/(x0+x1+x2);
  if (p == 0){
    float* o = out + (size_t)(row0+row)*3;
    o[0]=x0*inv; o[1]=x1*inv; o[2]=x2*inv;
  }
}

// ---------------- main: 128 threads = 2 independent waves, 16 rows each ----------------
__global__ __launch_bounds__(128, 3) void moct_kernel(
  const float* __restrict__ q, const float* __restrict__ k, const float* __restrict__ v,
  const float* __restrict__ g_mha, const float* __restrict__ b_mha,
  const float* __restrict__ b1, const float* __restrict__ b2,
  const float* __restrict__ g_pff, const float* __restrict__ b_pff,
  const float* __restrict__ b1p, const float* __restrict__ b2p,
  const float* __restrict__ g_pff1, const float* __restrict__ b_pff1,
  const float* __restrict__ bc1, const float* __restrict__ Wc2, const float* __restrict__ bc2,
  const unsigned short* __restrict__ wf,
  float* __restrict__ out)
{
  __shared__ __align__(16) unsigned short smem[2*WSM];
  const int tid = threadIdx.x, wv = tid>>6, wtid = tid&63;
  unsigned short* sm = smem + wv*WSM;
  const int m15 = wtid & 15, quad = wtid >> 4;
  const int row0 = blockIdx.x*32 + wv*16;

  // X30 k-pad (shorts 30,31 of each of 48 rows) = 0 once; never overwritten after.
  if (wtid < 48) *(unsigned*)(sm + X30 + wtid*S_P + 30) = 0u;

  // ---- stage 1: MHA(q,k,v); A-fragments straight from global ----
  #pragma unroll 1
  for (int b=0; b<3; ++b){
    float res[10];
    if (wtid < 48){                                   // fp32 residual (= q slice)
      int r = wtid/3, s = wtid - 3*r;
      const float2* rp = (const float2*)(q + (size_t)(row0+r)*90 + b*30 + s*10);
      #pragma unroll
      for (int e=0;e<5;++e){ float2 t=rp[e]; res[2*e]=t.x; res[2*e+1]=t.y; }
    }
    #pragma unroll 1
    for (int w=0; w<3; ++w){
      const float* T = (w==0)?q:(w==1)?k:v;
      short8v Bf = ldB(wf, w, wtid);
      #pragma unroll
      for (int mt=0; mt<3; ++mt){
        int sr = mt*16 + m15, rl = sr/3, s = sr - 3*rl;
        const float* src = T + (size_t)(row0+rl)*90 + b*30 + s*10;
        unsigned a0=0u, a1=0u, a2=0u, a3=0u;
        if (quad == 0){
          const float2* sp = (const float2*)src;
          float2 u0=sp[0], u1=sp[1], u2=sp[2], u3=sp[3];
          a0=pack2(u0.x,u0.y); a1=pack2(u1.x,u1.y);
          a2=pack2(u2.x,u2.y); a3=pack2(u3.x,u3.y);
        } else if (quad == 1){
          float2 u = ((const float2*)src)[4];
          a0 = pack2(u.x,u.y);                        // k=8,9; rest zero (B rows k>=10 are 0)
        }
        uint4v av = {a0,a1,a2,a3};
        short8v A; __builtin_memcpy(&A, &av, 16);
        f32x4 c = {0.f,0.f,0.f,0.f};
        c = MFMA(A, Bf, c);
        if (m15 < 10){
          #pragma unroll
          for (int rg=0; rg<4; ++rg)
            sm[QH + w*672 + (mt*16+quad*4+rg)*S_Q + m15] = f2b(c[rg]);
        }
      }
    }
    attn_phase<true>(sm, wtid, b, res, g_mha, b_mha);
  }

  // ---- stage 2: PFF30 (in-place x30) ----
  pff30<false>(sm, wtid, wf, b1, b2, g_pff, b_pff);

  // ---- stage 3: MHA(x,x,x) ----
  #pragma unroll 1
  for (int b=0; b<3; ++b){
    if (wtid < 48){   // repack x30 branch b -> PROJ seq-rows (pads: finite leftovers x zero B rows)
      int r = wtid/3, s = wtid - 3*r;
      const unsigned* sp = (const unsigned*)(sm + X30 + (b*16+r)*S_P + s*10);
      unsigned* dp = (unsigned*)(sm + PROJ + wtid*S_P);
      #pragma unroll
      for (int e=0; e<5; ++e) dp[e] = sp[e];
    }
    short8v B0 = ldB(wf,0,wtid), B1 = ldB(wf,1,wtid), B2 = ldB(wf,2,wtid);
    #pragma unroll
    for (int mt=0; mt<3; ++mt){
      short8v A = ldA(sm+PROJ, mt*16, S_P, 0, wtid);
      f32x4 c0={0.f,0.f,0.f,0.f}, c1={0.f,0.f,0.f,0.f}, c2={0.f,0.f,0.f,0.f};
      c0 = MFMA(A,B0,c0); c1 = MFMA(A,B1,c1); c2 = MFMA(A,B2,c2);
      if (m15 < 10){
        #pragma unroll
        for (int rg=0; rg<4; ++rg){
          int rw = mt*16 + quad*4 + rg;
          sm[QH + rw*S_Q + m15] = f2b(c0[rg]);
          sm[KH + rw*S_Q + m15] = f2b(c1[rg]);
          sm[VH + rw*S_Q + m15] = f2b(c2[rg]);
        }
      }
    }
    attn_phase<false>(sm, wtid, b, nullptr, g_mha, b_mha);
  }

  // X90 k-pad cols 92..95 (words 46,47 per row) = 0; region aliased QKV until now.
  if (wtid < 32)
    ((unsigned*)sm)[1920 + (wtid>>1)*52 + 46 + (wtid&1)] = 0u;

  // ---- stage 4: PFF30 -> x90 (QKV region, dead after stage 3) ----
  pff30<true>(sm, wtid, wf, b1, b2, g_pff, b_pff);
  // ---- stage 5: PFF90 (x90 in-place; H90 in PROJ) ----
  pff90(sm, wtid, wf, b1p, b2p, g_pff1, b_pff1);
  // ---- classifier + softmax ----
  classifier(sm, wtid, wf, bc1, Wc2, bc2, out, row0);
}

extern "C" void kernel_launch(void* const* d_in, const int* in_sizes, int n_in,
                              void* d_out, int out_size, void* d_ws, size_t ws_size,
                              hipStream_t stream)
{
  const float* q     = (const float*)d_in[0];
  const float* k     = (const float*)d_in[1];
  const float* v     = (const float*)d_in[2];
  const float* Wq    = (const float*)d_in[3];
  const float* Wk    = (const float*)d_in[4];
  const float* Wv    = (const float*)d_in[5];
  const float* g_mha = (const float*)d_in[6];
  const float* b_mha = (const float*)d_in[7];
  const float* W1    = (const float*)d_in[8];
  const float* b1    = (const float*)d_in[9];
  const float* W2    = (const float*)d_in[10];
  const float* b2    = (const float*)d_in[11];
  const float* g_pff = (const float*)d_in[12];
  const float* b_pff = (const float*)d_in[13];
  const float* W1p   = (const float*)d_in[14];
  const float* b1p   = (const float*)d_in[15];
  const float* W2p   = (const float*)d_in[16];
  const float* b2p   = (const float*)d_in[17];
  const float* g_pff1= (const float*)d_in[18];
  const float* b_pff1= (const float*)d_in[19];
  const float* Wc1   = (const float*)d_in[20];
  const float* bc1   = (const float*)d_in[21];
  const float* Wc2   = (const float*)d_in[22];
  const float* bc2   = (const float*)d_in[23];

  unsigned short* wf = (unsigned short*)d_ws;
  const int nrows = in_sizes[0] / 90;

  hipLaunchKernelGGL(prep_kernel, dim3((NFRAG*512 + 255)/256), dim3(256), 0, stream,
                     Wq, Wk, Wv, W1, W2, W1p, W2p, Wc1, wf);

  hipLaunchKernelGGL(moct_kernel, dim3(nrows/32), dim3(128), 0, stream,
    q, k, v, g_mha, b_mha, b1, b2, g_pff, b_pff,
    b1p, b2p, g_pff1, b_pff1, bc1, Wc2, bc2, wf, (float*)d_out);
}